// Round 12
// baseline (44.534 us; speedup 1.0000x reference)
//
#include <hip/hip_runtime.h>

// ADDA local attention, K=3, dilation=1, head_dim=64.
// q,k,v = [B=8, d=512, H=56, W=56] fp32 (channel-major), out = [B,H,W,512] fp32.
//
// R12 = R11 (DPP-tap row-wave kernel, 44.3 us) + :
//  - BAND=2 -> 1792 blocks = exactly 7 blocks/CU (kills the 3.5-blocks/CU tail)
//  - bijective XCD swizzle: same-bh bands run consecutively on one XCD, so
//    the 3x halo row re-reads hit the 4MB private L2 (one bh k+v+q = 2.4MB)
//  - pass-1 unroll 16 -> 64 loads in flight per batch
// Wave = one image row (lane = x). Per (c,row): 1 coalesced dword load +
// 2 DPP shifts + 3 FMAs. No k/v LDS, no barriers. LDS only for the per-wave
// store-transpose. Boundary taps masked to exact zero (= zero-padded unfold).

namespace {

constexpr int HD = 64, HH = 56, WW = 56, HW = HH * WW;
constexpr int CS = HW, DTOT = 512;
constexpr float SCALE = 0.125f;
constexpr int BAND = 2, NB = HH / BAND;  // 2 rows per block (2 waves), 28 bands
constexpr int PXW = 36;                  // padded px stride in transpose LDS

// value of this row at x-1 (lane i <- lane i-1): wave_shr:1 = 0x138
__device__ __forceinline__ float tapL(float v) {
  int i = __float_as_int(v);
  return __int_as_float(__builtin_amdgcn_update_dpp(i, i, 0x138, 0xF, 0xF, false));
}
// value of this row at x+1 (lane i <- lane i+1): wave_shl:1 = 0x130
__device__ __forceinline__ float tapR(float v) {
  int i = __float_as_int(v);
  return __int_as_float(__builtin_amdgcn_update_dpp(i, i, 0x130, 0xF, 0xF, false));
}

__global__ __launch_bounds__(128)
void adda_fwd(const float* __restrict__ qg, const float* __restrict__ kg,
              const float* __restrict__ vg, float* __restrict__ outg) {
  __shared__ float sm[BAND][64 * PXW];   // 18432 B, per-wave regions

  // XCD-aware bijective swizzle (gridDim.x = 1792 = 8*224): blocks of one
  // bh-plane run consecutively on the same XCD -> halo re-reads hit its L2.
  int wg = (int)blockIdx.x;
  const int nwg = (int)gridDim.x;
  if ((nwg & 7) == 0) wg = (wg & 7) * (nwg >> 3) + (wg >> 3);

  const int band = wg % NB;
  const int bh   = wg / NB;              // b*8 + head
  const int l    = (int)threadIdx.x & 63;
  const int wv   = (int)threadIdx.x >> 6;
  const int y    = band * BAND + wv;     // this wave's row
  const int x    = l < WW ? l : WW - 1;  // lanes 56-63 clone x=55 (not stored)

  const long base = (long)bh * HD * HW;
  const int gym = y > 0 ? y - 1 : 0;        // clamped row addresses (OOB rows
  const int gyp = y < HH - 1 ? y + 1 : y;   // masked to 0 below)

  const float* __restrict__ qp = qg + base + y * WW + x;
  const float* __restrict__ k0 = kg + base + gym * WW + x;
  const float* __restrict__ k1 = kg + base + y   * WW + x;
  const float* __restrict__ k2 = kg + base + gyp * WW + x;

  // ---- pass 1: logits; 1 load + 2 DPP + 3 FMA per (c,row) ----
  float lg[9];
#pragma unroll
  for (int n = 0; n < 9; ++n) lg[n] = 0.f;

#pragma unroll 16
  for (int c = 0; c < HD; ++c) {
    const float qv = qp[c * CS];
    const float a0 = k0[c * CS], a1 = k1[c * CS], a2 = k2[c * CS];
    lg[0] = fmaf(qv, tapL(a0), lg[0]);   // (dy=-1, dx=-1)
    lg[1] = fmaf(qv, a0,       lg[1]);   // (dy=-1, dx= 0)
    lg[2] = fmaf(qv, tapR(a0), lg[2]);   // (dy=-1, dx=+1)
    lg[3] = fmaf(qv, tapL(a1), lg[3]);
    lg[4] = fmaf(qv, a1,       lg[4]);
    lg[5] = fmaf(qv, tapR(a1), lg[5]);
    lg[6] = fmaf(qv, tapL(a2), lg[6]);
    lg[7] = fmaf(qv, a2,       lg[7]);
    lg[8] = fmaf(qv, tapR(a2), lg[8]);
  }

  // ---- softmax with zero-padded-unfold masking (OOB logit = exact 0) ----
  const bool okt = y > 0, okb = y < HH - 1, okl = x > 0, okr = x < WW - 1;
  const bool ok[9] = {okt && okl, okt, okt && okr,
                      okl,        true, okr,
                      okb && okl, okb, okb && okr};
  float w[9];
  float mx = 0.f;   // zeros (OOB logits) participate in the max
#pragma unroll
  for (int n = 0; n < 9; ++n) { w[n] = ok[n] ? lg[n] * SCALE : 0.f; mx = fmaxf(mx, w[n]); }
  float sum = 0.f;
#pragma unroll
  for (int n = 0; n < 9; ++n) { w[n] = __expf(w[n] - mx); sum += w[n]; }
  const float inv = 1.f / sum;
#pragma unroll
  for (int n = 0; n < 9; ++n) w[n] = ok[n] ? w[n] * inv : 0.f;  // OOB v = 0

  const float* __restrict__ v0 = vg + base + gym * WW + x;
  const float* __restrict__ v1 = vg + base + y   * WW + x;
  const float* __restrict__ v2 = vg + base + gyp * WW + x;

  float* __restrict__ smw = &sm[wv][0];
  float* __restrict__ ob =
      outg + ((long)(bh >> 3) * HW + y * WW) * DTOT + (bh & 7) * HD;

  // ---- pass 2 + store-transpose, in 2 chunks of 32 channels ----
#pragma unroll
  for (int half = 0; half < 2; ++half) {
    const int ch0 = half * 32;
    float o[32];
#pragma unroll
    for (int cc = 0; cc < 32; ++cc) {
      const int c = ch0 + cc;
      const float a0 = v0[c * CS], a1 = v1[c * CS], a2 = v2[c * CS];
      float acc;
      acc = w[0] * tapL(a0);
      acc = fmaf(w[1], a0,       acc);
      acc = fmaf(w[2], tapR(a0), acc);
      acc = fmaf(w[3], tapL(a1), acc);
      acc = fmaf(w[4], a1,       acc);
      acc = fmaf(w[5], tapR(a1), acc);
      acc = fmaf(w[6], tapL(a2), acc);
      acc = fmaf(w[7], a2,       acc);
      acc = fmaf(w[8], tapR(a2), acc);
      o[cc] = acc;
    }
    // lane (=px) dumps its 32 channels; same-wave LDS ops are ordered,
    // so no barrier is needed (per-wave region).
#pragma unroll
    for (int i = 0; i < 8; ++i)
      *(float4*)&smw[l * PXW + i * 4] =
          make_float4(o[i * 4], o[i * 4 + 1], o[i * 4 + 2], o[i * 4 + 3]);
    // cooperative write-out: 56 px x 128B contiguous per px = full lines;
    // 448 float4s over 64 lanes = exactly 7 rounds, all lanes active.
#pragma unroll
    for (int r = 0; r < 7; ++r) {
      const int g = r * 64 + l, px = g >> 3, slot = g & 7;
      const float4 t = *(const float4*)&smw[px * PXW + slot * 4];
      *(float4*)(ob + (long)px * DTOT + ch0 + slot * 4) = t;
    }
  }
}

} // namespace

extern "C" void kernel_launch(void* const* d_in, const int* in_sizes, int n_in,
                              void* d_out, int out_size, void* d_ws, size_t ws_size,
                              hipStream_t stream) {
  const float* q = (const float*)d_in[0];
  const float* k = (const float*)d_in[1];
  const float* v = (const float*)d_in[2];
  float* out = (float*)d_out;

  const int BH = in_sizes[0] / (HD * HW);  // B * 8 heads = 64
  dim3 grid(BH * NB);                       // 1792 = 8 * 224
  adda_fwd<<<grid, 128, 0, stream>>>(q, k, v, out);
}